// Round 6
// baseline (2103.273 us; speedup 1.0000x reference)
//
#include <hip/hip_runtime.h>
#include <math.h>

#define TW 64
#define TH 32
#define IMG 1024

// LDS row strides (floats). Row-stride mod 32 an odd multiple of 4 so
// consecutive rows shift bank-quads: 84%32=20, 68%32=4.
#define GSTR 84   // gray: 48 rows  (gy = y0-8 .. y0+39, gx = x0-8 .. x0+75)
#define ASTR 84   // A (vblur): 35 rows (34 used + 1 guard), ar -> gy = y0-1+ar
#define SSTR 68   // S (smooth): 34 rows, cs -> gx = x0-1+cs

// ---- compile-time Gaussian weight table (doubles, then normalized to float).
// Indexed ONLY with compile-time constants -> every weight folds to an inline
// 32-bit literal in v_fmac_f32; no LDS table, no registers, no expf preamble.
constexpr double cexp_pos(double t) {   // e^t for t >= 0 via Taylor (double)
  double term = 1.0, sum = 1.0;
  for (int i = 1; i < 120; ++i) {
    term *= t / i;
    sum += term;
    if (term < 1e-300) break;
  }
  return sum;
}
constexpr double cexp(double t) { return t < 0 ? 1.0 / cexp_pos(-t) : cexp_pos(t); }

struct WTab {
  float w[189];
  constexpr WTab() : w{} {
    int off = 0;
    for (int ki = 0; ki < 7; ++ki) {          // ks = 3 + 2*ki, r = ks/2
      const int ks = 3 + 2 * ki, r = ks >> 1;
      for (int si = 0; si < 3; ++si) {        // sigma = 1 + si
        const double s = (double)(1 + si);
        double tmp[15] = {};
        double sum = 0.0;
        for (int i = 0; i < ks; ++i) {
          const double x = (double)(i - r);
          tmp[i] = cexp(-x * x / (2.0 * s * s));
          sum += tmp[i];
        }
        for (int i = 0; i < ks; ++i) w[off + i] = (float)(tmp[i] / sum);
        off += ks;
      }
    }
  }
};
constexpr WTab WT{};

// Per-scale processing. R = radius (ksize = 2R+1), OFF = offset into WT.w.
template<int R, int OFF>
__device__ __forceinline__ void do_scale(
    const float* __restrict__ gray, float* __restrict__ A, float* __restrict__ S,
    int tid, int x0, int y0, float* __restrict__ acc)
{
  // ---- P1: vertical blur gray -> A. 20 quads x 9 row-segments (8x G=4 + 1x G=2).
  if (tid < 180) {
    const int q   = tid % 20;
    const int seg = tid / 20;
    const int ys  = seg * 4;                 // first A-row of this segment
    const bool full = (seg < 8);             // seg 8 computes only rows 32,33
    float4 a4[4];
#pragma unroll
    for (int gi = 0; gi < 4; ++gi) a4[gi] = make_float4(0.f, 0.f, 0.f, 0.f);
#pragma unroll
    for (int kk = 0; kk < 4 + 2*R; ++kk) {
      const bool kok = (kk < 2 + 2*R);
      if (full || kok) {
        const float4 v = *(const float4*)&gray[(ys + 7 - R + kk)*GSTR + 4*q];
#pragma unroll
        for (int gi = 0; gi < 4; ++gi) {
          const int d = kk - gi;             // tap index 0..2R (compile-time)
          if (d >= 0 && d <= 2*R) {
            if (gi < 2 || full) {
              const float wt = WT.w[OFF + d];   // inline literal
              a4[gi].x += wt * v.x;
              a4[gi].y += wt * v.y;
              a4[gi].z += wt * v.z;
              a4[gi].w += wt * v.w;
            }
          }
        }
      }
    }
#pragma unroll
    for (int gi = 0; gi < 4; ++gi)
      if (gi < 2 || full)
        *(float4*)&A[(ys + gi)*ASTR + 4*q] = a4[gi];
  }
  __syncthreads();

  // ---- P2: horizontal blur A -> S (34 rows x 66 cols), force 0 outside image.
  // ar = u%34: consecutive lanes step ROWS (bank step 20) -> conflict-free.
  {
    constexpr int Q0   = (7 - R) >> 2;                 // first quad rel. to col 8*cg
    constexpr int NQ   = ((14 + R) >> 2) - Q0 + 1;     // quads to load (3..6)
    constexpr int BASE = 7 - R - 4*Q0;                 // av index base
#pragma unroll 1
    for (int u = tid; u < 306; u += 256) {             // 34 rows * 9 col-groups
      const int ar = u % 34, cg = u / 34;
      float av[4*NQ];
#pragma unroll
      for (int i = 0; i < NQ; ++i)
        *(float4*)&av[4*i] = *(const float4*)&A[ar*ASTR + 8*cg + 4*(Q0 + i)];
      const int gy  = y0 - 1 + ar;
      const int gx0 = x0 - 1 + 8*cg;
      const bool rowok = ((unsigned)gy < (unsigned)IMG);
      float o8[8];
#pragma unroll
      for (int o = 0; o < 8; ++o) {
        float s = 0.f;
#pragma unroll
        for (int t = 0; t <= 2*R; ++t)
          s += WT.w[OFF + t] * av[o + BASE + t];       // inline literals
        const int gx = gx0 + o;
        // Laplacian input is smooth zero-padded by 1: outside-image slots are 0.
        o8[o] = (rowok && ((unsigned)gx < (unsigned)IMG)) ? s : 0.f;
      }
      if (cg < 8) {
        *(float4*)&S[ar*SSTR + 8*cg]     = make_float4(o8[0], o8[1], o8[2], o8[3]);
        *(float4*)&S[ar*SSTR + 8*cg + 4] = make_float4(o8[4], o8[5], o8[6], o8[7]);
      } else {                                          // last group: cols 64,65
        S[ar*SSTR + 64] = o8[0];
        S[ar*SSTR + 65] = o8[1];
      }
    }
  }
  __syncthreads();

  // ---- P3: 5-point Laplacian of S; accumulate |log| into VGPR acc.
  // row = tid&31: consecutive lanes step rows (bank step 4) -> conflict-free.
  {
    const int row = tid & 31, cg = tid >> 5;
    float T[12], M[12], B[12];
#pragma unroll
    for (int i = 0; i < 3; ++i) {
      *(float4*)&T[4*i] = *(const float4*)&S[(row    )*SSTR + 8*cg + 4*i];
      *(float4*)&M[4*i] = *(const float4*)&S[(row + 1)*SSTR + 8*cg + 4*i];
      *(float4*)&B[4*i] = *(const float4*)&S[(row + 2)*SSTR + 8*cg + 4*i];
    }
#pragma unroll
    for (int o = 0; o < 8; ++o) {
      const int j = o + 1;
      const float lg = T[j] + B[j] + M[j-1] + M[j+1] - 4.f*M[j];
      acc[o] += fabsf(lg);
    }
  }
  // NO barrier here: next P1 writes A (disjoint from S); the post-P1 barrier
  // orders this P3's S-reads against the next P2's S-writes.
}

__global__ __launch_bounds__(256, 4)
void MultiscaleLoG_kernel(const float* __restrict__ in, float* __restrict__ out)
{
  __shared__ __align__(16) float gray[48*GSTR];
  __shared__ __align__(16) float A[35*ASTR];
  __shared__ __align__(16) float S[34*SSTR];

  const int tid = threadIdx.x;
  const int x0 = blockIdx.x * TW;
  const int y0 = blockIdx.y * TH;
  const int b  = blockIdx.z;
  const float* __restrict__ base = in + (size_t)b * 3u * 1048576u;

  // ---- gray = channel mean, staged with halo; zero outside image
  const bool interior = (x0 >= 8) & (x0 + 76 <= IMG) & (y0 >= 8) & (y0 + 40 <= IMG);
#pragma unroll 1
  for (int u = tid; u < 960; u += 256) {          // 20 quads x 48 rows
    const int q = u % 20, gr = u / 20;
    const int gx = x0 - 8 + 4*q, gy = y0 - 8 + gr;
    float4 v;
    if (interior) {
      const float* p = base + (size_t)gy * IMG + gx;
      const float4 c0 = *(const float4*)p;
      const float4 c1 = *(const float4*)(p + 1048576);
      const float4 c2 = *(const float4*)(p + 2097152);
      v.x = (c0.x + c1.x + c2.x) * (1.f/3.f);
      v.y = (c0.y + c1.y + c2.y) * (1.f/3.f);
      v.z = (c0.z + c1.z + c2.z) * (1.f/3.f);
      v.w = (c0.w + c1.w + c2.w) * (1.f/3.f);
    } else {
      float t4[4];
#pragma unroll
      for (int j = 0; j < 4; ++j) {
        const int xx = gx + j;
        float s = 0.f;
        if ((unsigned)xx < (unsigned)IMG && (unsigned)gy < (unsigned)IMG) {
          const float* p = base + (size_t)gy * IMG + xx;
          s = (p[0] + p[1048576] + p[2097152]) * (1.f/3.f);
        }
        t4[j] = s;
      }
      v = make_float4(t4[0], t4[1], t4[2], t4[3]);
    }
    *(float4*)&gray[gr*GSTR + 4*q] = v;
  }
  __syncthreads();

  float acc[8];
#pragma unroll
  for (int i = 0; i < 8; ++i) acc[i] = 0.f;

#define DO_KS(R, KOFF) \
  do_scale<R, (KOFF)>(gray, A, S, tid, x0, y0, acc); \
  do_scale<R, (KOFF) + (2*(R)+1)>(gray, A, S, tid, x0, y0, acc); \
  do_scale<R, (KOFF) + 2*(2*(R)+1)>(gray, A, S, tid, x0, y0, acc);

  DO_KS(1, 0)
  DO_KS(2, 9)
  DO_KS(3, 24)
  DO_KS(4, 45)
  DO_KS(5, 72)
  DO_KS(6, 105)
  DO_KS(7, 144)
#undef DO_KS

  // ---- coalesced output via LDS transpose (acc ownership is row=tid&31)
  __syncthreads();                         // all P3 S-reads done before overwrite
  {
    const int row = tid & 31, cg = tid >> 5;
    *(float4*)&S[row*SSTR + 8*cg]     = make_float4(acc[0], acc[1], acc[2], acc[3]);
    *(float4*)&S[row*SSTR + 8*cg + 4] = make_float4(acc[4], acc[5], acc[6], acc[7]);
  }
  __syncthreads();
  {
    const int cg = tid & 7, row = tid >> 3;
    const float4 lo = *(const float4*)&S[row*SSTR + 8*cg];
    const float4 hi = *(const float4*)&S[row*SSTR + 8*cg + 4];
    float* op = out + ((size_t)b * IMG + (y0 + row)) * IMG + x0 + 8*cg;
    *(float4*)&op[0] = lo;
    *(float4*)&op[4] = hi;
  }
}

extern "C" void kernel_launch(void* const* d_in, const int* in_sizes, int n_in,
                              void* d_out, int out_size, void* d_ws, size_t ws_size,
                              hipStream_t stream) {
  (void)in_sizes; (void)n_in; (void)d_ws; (void)ws_size; (void)out_size;
  const float* in = (const float*)d_in[0];
  float* out = (float*)d_out;
  dim3 grid(IMG / TW, IMG / TH, 16);
  MultiscaleLoG_kernel<<<grid, dim3(256), 0, stream>>>(in, out);
}

// Round 7
// 1413.755 us; speedup vs baseline: 1.4877x; 1.4877x over previous
//
#include <hip/hip_runtime.h>
#include <math.h>

#define TW 64
#define TH 32
#define IMG 1024

// LDS row strides (floats). Row-stride mod 32 an odd multiple of 4 so
// consecutive rows shift bank-quads: 84%32=20, 68%32=4.
#define GSTR 84   // gray: 48 rows  (gy = y0-8 .. y0+39, gx = x0-8 .. x0+75)
#define ASTR 84   // A (vblur): 35 rows (34 used + 1 guard), ar -> gy = y0-1+ar
#define SSTR 68   // S (smooth): 34 rows, cs -> gx = x0-1+cs

// ---- compile-time Gaussian weight table (doubles, then normalized to float).
// Indexed ONLY with compile-time constants -> every weight folds to an inline
// 32-bit literal in v_fmac_f32; no LDS table, no registers, no expf preamble.
constexpr double cexp_pos(double t) {   // e^t for t >= 0 via Taylor (double)
  double term = 1.0, sum = 1.0;
  for (int i = 1; i < 120; ++i) {
    term *= t / i;
    sum += term;
    if (term < 1e-300) break;
  }
  return sum;
}
constexpr double cexp(double t) { return t < 0 ? 1.0 / cexp_pos(-t) : cexp_pos(t); }

struct WTab {
  float w[189];
  constexpr WTab() : w{} {
    int off = 0;
    for (int ki = 0; ki < 7; ++ki) {          // ks = 3 + 2*ki, r = ks/2
      const int ks = 3 + 2 * ki, r = ks >> 1;
      for (int si = 0; si < 3; ++si) {        // sigma = 1 + si
        const double s = (double)(1 + si);
        double tmp[15] = {};
        double sum = 0.0;
        for (int i = 0; i < ks; ++i) {
          const double x = (double)(i - r);
          tmp[i] = cexp(-x * x / (2.0 * s * s));
          sum += tmp[i];
        }
        for (int i = 0; i < ks; ++i) w[off + i] = (float)(tmp[i] / sum);
        off += ks;
      }
    }
  }
};
constexpr WTab WT{};

// Per-scale processing. R = radius (ksize = 2R+1), OFF = offset into WT.w.
template<int R, int OFF>
__device__ __forceinline__ void do_scale(
    const float* __restrict__ gray, float* __restrict__ A, float* __restrict__ S,
    int tid, int x0, int y0, float* __restrict__ acc)
{
  // ---- P1: vertical blur gray -> A. 20 quads x 9 row-segments (8x G=4 + 1x G=2).
  if (tid < 180) {
    const int q   = tid % 20;
    const int seg = tid / 20;
    const int ys  = seg * 4;                 // first A-row of this segment
    const bool full = (seg < 8);             // seg 8 computes only rows 32,33
    float4 a4[4];
#pragma unroll
    for (int gi = 0; gi < 4; ++gi) a4[gi] = make_float4(0.f, 0.f, 0.f, 0.f);
#pragma unroll
    for (int kk = 0; kk < 4 + 2*R; ++kk) {
      const bool kok = (kk < 2 + 2*R);
      if (full || kok) {
        const float4 v = *(const float4*)&gray[(ys + 7 - R + kk)*GSTR + 4*q];
#pragma unroll
        for (int gi = 0; gi < 4; ++gi) {
          const int d = kk - gi;             // tap index 0..2R (compile-time)
          if (d >= 0 && d <= 2*R) {
            if (gi < 2 || full) {
              const float wt = WT.w[OFF + d];   // inline literal
              a4[gi].x += wt * v.x;
              a4[gi].y += wt * v.y;
              a4[gi].z += wt * v.z;
              a4[gi].w += wt * v.w;
            }
          }
        }
      }
    }
#pragma unroll
    for (int gi = 0; gi < 4; ++gi)
      if (gi < 2 || full)
        *(float4*)&A[(ys + gi)*ASTR + 4*q] = a4[gi];
  }
  __syncthreads();

  // ---- P2: horizontal blur A -> S (34 rows x 66 cols), force 0 outside image.
  // ar = u%34: consecutive lanes step ROWS (bank step 20) -> conflict-free.
  {
    constexpr int Q0   = (7 - R) >> 2;                 // first quad rel. to col 8*cg
    constexpr int NQ   = ((14 + R) >> 2) - Q0 + 1;     // quads to load (3..6)
    constexpr int BASE = 7 - R - 4*Q0;                 // av index base
#pragma unroll 1
    for (int u = tid; u < 306; u += 256) {             // 34 rows * 9 col-groups
      const int ar = u % 34, cg = u / 34;
      float av[4*NQ];
#pragma unroll
      for (int i = 0; i < NQ; ++i)
        *(float4*)&av[4*i] = *(const float4*)&A[ar*ASTR + 8*cg + 4*(Q0 + i)];
      const int gy  = y0 - 1 + ar;
      const int gx0 = x0 - 1 + 8*cg;
      const bool rowok = ((unsigned)gy < (unsigned)IMG);
      float o8[8];
#pragma unroll
      for (int o = 0; o < 8; ++o) {
        float s = 0.f;
#pragma unroll
        for (int t = 0; t <= 2*R; ++t)
          s += WT.w[OFF + t] * av[o + BASE + t];       // inline literals
        const int gx = gx0 + o;
        // Laplacian input is smooth zero-padded by 1: outside-image slots are 0.
        o8[o] = (rowok && ((unsigned)gx < (unsigned)IMG)) ? s : 0.f;
      }
      if (cg < 8) {
        *(float4*)&S[ar*SSTR + 8*cg]     = make_float4(o8[0], o8[1], o8[2], o8[3]);
        *(float4*)&S[ar*SSTR + 8*cg + 4] = make_float4(o8[4], o8[5], o8[6], o8[7]);
      } else {                                          // last group: cols 64,65
        S[ar*SSTR + 64] = o8[0];
        S[ar*SSTR + 65] = o8[1];
      }
    }
  }
  __syncthreads();

  // ---- P3: 5-point Laplacian of S; accumulate |log| into VGPR acc.
  // row = tid&31: consecutive lanes step rows (bank step 4) -> conflict-free.
  {
    const int row = tid & 31, cg = tid >> 5;
    float T[12], M[12], B[12];
#pragma unroll
    for (int i = 0; i < 3; ++i) {
      *(float4*)&T[4*i] = *(const float4*)&S[(row    )*SSTR + 8*cg + 4*i];
      *(float4*)&M[4*i] = *(const float4*)&S[(row + 1)*SSTR + 8*cg + 4*i];
      *(float4*)&B[4*i] = *(const float4*)&S[(row + 2)*SSTR + 8*cg + 4*i];
    }
#pragma unroll
    for (int o = 0; o < 8; ++o) {
      const int j = o + 1;
      const float lg = T[j] + B[j] + M[j-1] + M[j+1] - 4.f*M[j];
      acc[o] += fabsf(lg);
    }
  }
  // NO barrier here: next P1 writes A (disjoint from S); the post-P1 barrier
  // orders this P3's S-reads against the next P2's S-writes.
}

// NOTE on the bound: hipcc maps the 2nd arg N to a VGPR cap of ~256/N.
// N=4 -> cap 64 (catastrophic spills, R2/R6); N=1 -> 256 (spills acc, R3);
// N=2 -> cap 128: fits natural demand (~90) AND 128 is exactly the 4-waves/
// SIMD threshold, so runtime occupancy is LDS-limited at 4 blocks/CU.
__global__ __launch_bounds__(256, 2)
void MultiscaleLoG_kernel(const float* __restrict__ in, float* __restrict__ out)
{
  __shared__ __align__(16) float gray[48*GSTR];
  __shared__ __align__(16) float A[35*ASTR];
  __shared__ __align__(16) float S[34*SSTR];

  const int tid = threadIdx.x;
  const int x0 = blockIdx.x * TW;
  const int y0 = blockIdx.y * TH;
  const int b  = blockIdx.z;
  const float* __restrict__ base = in + (size_t)b * 3u * 1048576u;

  // ---- gray = channel mean, staged with halo; zero outside image
  const bool interior = (x0 >= 8) & (x0 + 76 <= IMG) & (y0 >= 8) & (y0 + 40 <= IMG);
#pragma unroll 1
  for (int u = tid; u < 960; u += 256) {          // 20 quads x 48 rows
    const int q = u % 20, gr = u / 20;
    const int gx = x0 - 8 + 4*q, gy = y0 - 8 + gr;
    float4 v;
    if (interior) {
      const float* p = base + (size_t)gy * IMG + gx;
      const float4 c0 = *(const float4*)p;
      const float4 c1 = *(const float4*)(p + 1048576);
      const float4 c2 = *(const float4*)(p + 2097152);
      v.x = (c0.x + c1.x + c2.x) * (1.f/3.f);
      v.y = (c0.y + c1.y + c2.y) * (1.f/3.f);
      v.z = (c0.z + c1.z + c2.z) * (1.f/3.f);
      v.w = (c0.w + c1.w + c2.w) * (1.f/3.f);
    } else {
      float t4[4];
#pragma unroll
      for (int j = 0; j < 4; ++j) {
        const int xx = gx + j;
        float s = 0.f;
        if ((unsigned)xx < (unsigned)IMG && (unsigned)gy < (unsigned)IMG) {
          const float* p = base + (size_t)gy * IMG + xx;
          s = (p[0] + p[1048576] + p[2097152]) * (1.f/3.f);
        }
        t4[j] = s;
      }
      v = make_float4(t4[0], t4[1], t4[2], t4[3]);
    }
    *(float4*)&gray[gr*GSTR + 4*q] = v;
  }
  __syncthreads();

  float acc[8];
#pragma unroll
  for (int i = 0; i < 8; ++i) acc[i] = 0.f;

#define DO_KS(R, KOFF) \
  do_scale<R, (KOFF)>(gray, A, S, tid, x0, y0, acc); \
  do_scale<R, (KOFF) + (2*(R)+1)>(gray, A, S, tid, x0, y0, acc); \
  do_scale<R, (KOFF) + 2*(2*(R)+1)>(gray, A, S, tid, x0, y0, acc);

  DO_KS(1, 0)
  DO_KS(2, 9)
  DO_KS(3, 24)
  DO_KS(4, 45)
  DO_KS(5, 72)
  DO_KS(6, 105)
  DO_KS(7, 144)
#undef DO_KS

  // ---- coalesced output via LDS transpose (acc ownership is row=tid&31)
  __syncthreads();                         // all P3 S-reads done before overwrite
  {
    const int row = tid & 31, cg = tid >> 5;
    *(float4*)&S[row*SSTR + 8*cg]     = make_float4(acc[0], acc[1], acc[2], acc[3]);
    *(float4*)&S[row*SSTR + 8*cg + 4] = make_float4(acc[4], acc[5], acc[6], acc[7]);
  }
  __syncthreads();
  {
    const int cg = tid & 7, row = tid >> 3;
    const float4 lo = *(const float4*)&S[row*SSTR + 8*cg];
    const float4 hi = *(const float4*)&S[row*SSTR + 8*cg + 4];
    float* op = out + ((size_t)b * IMG + (y0 + row)) * IMG + x0 + 8*cg;
    *(float4*)&op[0] = lo;
    *(float4*)&op[4] = hi;
  }
}

extern "C" void kernel_launch(void* const* d_in, const int* in_sizes, int n_in,
                              void* d_out, int out_size, void* d_ws, size_t ws_size,
                              hipStream_t stream) {
  (void)in_sizes; (void)n_in; (void)d_ws; (void)ws_size; (void)out_size;
  const float* in = (const float*)d_in[0];
  float* out = (float*)d_out;
  dim3 grid(IMG / TW, IMG / TH, 16);
  MultiscaleLoG_kernel<<<grid, dim3(256), 0, stream>>>(in, out);
}

// Round 8
// 792.375 us; speedup vs baseline: 2.6544x; 1.7842x over previous
//
#include <hip/hip_runtime.h>
#include <math.h>

#define TW 64
#define TH 32
#define IMG 1024

#define GSTR 80    // gray: 48 rows x 80 cols (gx = x0-8 .. x0+71); wrap conflicts 2-way = free
#define ASTR 84    // A (vblur): 34 rows; 84%32=20 -> row-lane reads conflict-free
#define SSTR 68    // S rows; 68%32=4 -> row-lane reads 2-way = free; rows 16B-aligned
#define SMROWS 24  // S main buffer rows 0..23
#define PPROWS 10  // ping-pong buffers hold S rows 24..33
#define ACCSTR 12  // per-slot 8 floats @ stride 12 -> b128 2-way = free
#define WCUT 1e-5f // compile-time tap cutoff (error < 1e-3 vs 0.167 threshold)

// ---- compile-time Gaussian weights: indexed only with constants -> inline literals.
constexpr double cexp_pos(double t) {
  double term = 1.0, sum = 1.0;
  for (int i = 1; i < 120; ++i) { term *= t / i; sum += term; if (term < 1e-300) break; }
  return sum;
}
constexpr double cexp(double t) { return t < 0 ? 1.0 / cexp_pos(-t) : cexp_pos(t); }

struct WTab {
  float w[189];
  constexpr WTab() : w{} {
    int off = 0;
    for (int ki = 0; ki < 7; ++ki) {
      const int ks = 3 + 2 * ki, r = ks >> 1;
      for (int si = 0; si < 3; ++si) {
        const double s = (double)(1 + si);
        double tmp[15] = {}; double sum = 0.0;
        for (int i = 0; i < ks; ++i) {
          const double x = (double)(i - r);
          tmp[i] = cexp(-x * x / (2.0 * s * s)); sum += tmp[i];
        }
        for (int i = 0; i < ks; ++i) w[off + i] = (float)(tmp[i] / sum);
        off += ks;
      }
    }
  }
};
constexpr WTab WT{};

// ---- P1 item: vertical blur gray -> A. u in [0,180): 20 quads x 9 segs (8xG4 + 1xG2).
template<int R, int OFF>
__device__ __forceinline__ void p1_item(int u, const float* __restrict__ gray,
                                        float* __restrict__ A) {
  const int q = u % 20, seg = u / 20;
  const int ys = seg * 4;
  const bool full = (seg < 8);
  float4 a4[4];
#pragma unroll
  for (int gi = 0; gi < 4; ++gi) a4[gi] = make_float4(0.f, 0.f, 0.f, 0.f);
#pragma unroll
  for (int kk = 0; kk < 4 + 2*R; ++kk) {
    const bool kok = (kk < 2 + 2*R);
    if (full || kok) {
      const float4 v = *(const float4*)&gray[(ys + 7 - R + kk)*GSTR + 4*q];
#pragma unroll
      for (int gi = 0; gi < 4; ++gi) {
        const int d = kk - gi;
        if (d >= 0 && d <= 2*R) {
          if (WT.w[OFF + d] >= WCUT) {          // compile-time tap skip
            if (gi < 2 || full) {
              const float wt = WT.w[OFF + d];   // inline literal
              a4[gi].x += wt * v.x; a4[gi].y += wt * v.y;
              a4[gi].z += wt * v.z; a4[gi].w += wt * v.w;
            }
          }
        }
      }
    }
  }
#pragma unroll
  for (int gi = 0; gi < 4; ++gi)
    if (gi < 2 || full)
      *(float4*)&A[(ys + gi)*ASTR + 4*q] = a4[gi];
}

// ---- P2 item: horizontal blur A -> S (row ar of 34). Rows >= 24 go to ppW.
template<int R, int OFF>
__device__ __forceinline__ void p2_item(int u, const float* __restrict__ A,
    float* __restrict__ Sm, float* __restrict__ ppW, int x0, int y0) {
  constexpr int Q0   = (7 - R) >> 2;
  constexpr int NQ   = ((14 + R) >> 2) - Q0 + 1;
  constexpr int BASE = 7 - R - 4*Q0;
  const int ar = u % 34, cg = u / 34;
  float av[4*NQ];
#pragma unroll
  for (int i = 0; i < NQ; ++i)
    *(float4*)&av[4*i] = *(const float4*)&A[ar*ASTR + 8*cg + 4*(Q0 + i)];
  const int gy  = y0 - 1 + ar;
  const int gx0 = x0 - 1 + 8*cg;
  const bool rowok = ((unsigned)gy < (unsigned)IMG);
  float o8[8];
#pragma unroll
  for (int o = 0; o < 8; ++o) {
    float s = 0.f;
#pragma unroll
    for (int t = 0; t <= 2*R; ++t)
      if (WT.w[OFF + t] >= WCUT)               // compile-time tap skip
        s += WT.w[OFF + t] * av[o + BASE + t];
    const int gx = gx0 + o;
    o8[o] = (rowok && ((unsigned)gx < (unsigned)IMG)) ? s : 0.f;
  }
  float* wrow = (ar < SMROWS) ? &Sm[ar*SSTR] : &ppW[(ar - SMROWS)*SSTR];
  if (cg < 8) {
    *(float4*)&wrow[8*cg]     = make_float4(o8[0], o8[1], o8[2], o8[3]);
    *(float4*)&wrow[8*cg + 4] = make_float4(o8[4], o8[5], o8[6], o8[7]);
  } else {
    wrow[64] = o8[0];
    wrow[65] = o8[1];
  }
}

// ---- P3 item: 5-point Laplacian; |log| into LDS ACC slot i (= output index).
__device__ __forceinline__ void p3_item(int i, const float* __restrict__ Sm,
    const float* __restrict__ ppR, float* __restrict__ ACC) {
  const int row = i >> 3, cg = i & 7;          // row 0..31, cols 8cg..8cg+7
  const float* r0 = (row     < SMROWS) ? &Sm[(row    )*SSTR] : &ppR[(row     - SMROWS)*SSTR];
  const float* r1 = (row + 1 < SMROWS) ? &Sm[(row + 1)*SSTR] : &ppR[(row + 1 - SMROWS)*SSTR];
  const float* r2 = (row + 2 < SMROWS) ? &Sm[(row + 2)*SSTR] : &ppR[(row + 2 - SMROWS)*SSTR];
  float T[12], M[12], B[12];
#pragma unroll
  for (int k = 0; k < 3; ++k) {
    *(float4*)&T[4*k] = *(const float4*)&r0[8*cg + 4*k];
    *(float4*)&M[4*k] = *(const float4*)&r1[8*cg + 4*k];
    *(float4*)&B[4*k] = *(const float4*)&r2[8*cg + 4*k];
  }
  float4 aA = *(const float4*)&ACC[i*ACCSTR];
  float4 aB = *(const float4*)&ACC[i*ACCSTR + 4];
  float lg;
#define LAP(j) (T[j] + B[j] + M[(j)-1] + M[(j)+1] - 4.f*M[j])
  lg = LAP(1); aA.x += fabsf(lg);
  lg = LAP(2); aA.y += fabsf(lg);
  lg = LAP(3); aA.z += fabsf(lg);
  lg = LAP(4); aA.w += fabsf(lg);
  lg = LAP(5); aB.x += fabsf(lg);
  lg = LAP(6); aB.y += fabsf(lg);
  lg = LAP(7); aB.z += fabsf(lg);
  lg = LAP(8); aB.w += fabsf(lg);
#undef LAP
  *(float4*)&ACC[i*ACCSTR]     = aA;
  *(float4*)&ACC[i*ACCSTR + 4] = aB;
}

// ---- phase X: P1<scale s> (180) || P3 rows 0-23 of scale s-1 (192 items)
template<int R, int OFF, bool DO_P1, bool DO_P3>
__device__ __forceinline__ void phaseX(const float* __restrict__ gray,
    float* __restrict__ A, const float* __restrict__ Sm,
    const float* __restrict__ ppR, float* __restrict__ ACC, int tid) {
  if constexpr (DO_P1 && DO_P3) {
#pragma unroll 1
    for (int u = tid; u < 372; u += 256) {
      if (u < 180) p1_item<R, OFF>(u, gray, A);
      else         p3_item(u - 180, Sm, ppR, ACC);
    }
  } else if constexpr (DO_P1) {
    if (tid < 180) p1_item<R, OFF>(tid, gray, A);
  } else {
    if (tid < 192) p3_item(tid, Sm, ppR, ACC);
  }
}

// ---- phase Y: P2<scale s> (306) || P3 rows 24-31 of scale s-1 (64 items)
template<int R, int OFF, bool HAS_P3>
__device__ __forceinline__ void phaseY(const float* __restrict__ A,
    float* __restrict__ Sm, float* __restrict__ ppW, const float* __restrict__ ppR,
    float* __restrict__ ACC, int x0, int y0, int tid) {
  constexpr int NU = HAS_P3 ? 370 : 306;
#pragma unroll 1
  for (int u = tid; u < NU; u += 256) {
    if (u < 306) p2_item<R, OFF>(u, A, Sm, ppW, x0, y0);
    else         p3_item(192 + (u - 306), Sm, ppR, ACC);
  }
}

__global__ __launch_bounds__(256, 3)
void MultiscaleLoG_kernel(const float* __restrict__ in, float* __restrict__ out)
{
  __shared__ __align__(16) float gray[48*GSTR];   // 15360 B
  __shared__ __align__(16) float A[34*ASTR];      // 11424 B
  __shared__ __align__(16) float Sm[SMROWS*SSTR]; //  6528 B
  __shared__ __align__(16) float PP0[PPROWS*SSTR];//  2720 B
  __shared__ __align__(16) float PP1[PPROWS*SSTR];//  2720 B
  __shared__ __align__(16) float ACC[256*ACCSTR]; // 12288 B  -> total ~51.0 KB, 3 blocks/CU

  const int tid = threadIdx.x;
  const int x0 = blockIdx.x * TW;
  const int y0 = blockIdx.y * TH;
  const int b  = blockIdx.z;
  const float* __restrict__ base = in + (size_t)b * 3u * 1048576u;

  // zero own ACC slot (slot == tid == output index; pad floats 8..11 never read)
  *(float4*)&ACC[tid*ACCSTR]     = make_float4(0.f, 0.f, 0.f, 0.f);
  *(float4*)&ACC[tid*ACCSTR + 4] = make_float4(0.f, 0.f, 0.f, 0.f);

  // ---- stage gray = channel mean with halo (rows y0-8..y0+39, cols x0-8..x0+71)
  const bool interior = (x0 >= 8) & (x0 + 72 <= IMG) & (y0 >= 8) & (y0 + 40 <= IMG);
#pragma unroll 1
  for (int u = tid; u < 960; u += 256) {          // 20 quads x 48 rows
    const int q = u % 20, gr = u / 20;
    const int gx = x0 - 8 + 4*q, gy = y0 - 8 + gr;
    float4 v;
    if (interior) {
      const float* p = base + (size_t)gy * IMG + gx;
      const float4 c0 = *(const float4*)p;
      const float4 c1 = *(const float4*)(p + 1048576);
      const float4 c2 = *(const float4*)(p + 2097152);
      v.x = (c0.x + c1.x + c2.x) * (1.f/3.f);
      v.y = (c0.y + c1.y + c2.y) * (1.f/3.f);
      v.z = (c0.z + c1.z + c2.z) * (1.f/3.f);
      v.w = (c0.w + c1.w + c2.w) * (1.f/3.f);
    } else {
      float t4[4];
#pragma unroll
      for (int j = 0; j < 4; ++j) {
        const int xx = gx + j;
        float s = 0.f;
        if ((unsigned)xx < (unsigned)IMG && (unsigned)gy < (unsigned)IMG) {
          const float* p = base + (size_t)gy * IMG + xx;
          s = (p[0] + p[1048576] + p[2097152]) * (1.f/3.f);
        }
        t4[j] = s;
      }
      v = make_float4(t4[0], t4[1], t4[2], t4[3]);
    }
    *(float4*)&gray[gr*GSTR + 4*q] = v;
  }
  __syncthreads();

  // ---- pipelined scales. Per scale s: phaseX { P1<s> || P3rows0-23<s-1> } ; B ;
  //      phaseY { P2<s> || P3rows24-31<s-1> } ; B.
  // S rows 24..33 ping-pong between PP0/PP1 by scale parity so phaseY's P2<s>
  // never writes the buffer the straggler P3<s-1> is reading.
#define STEP0(RR, OO) \
  phaseX<RR, OO, true, false>(gray, A, Sm, PP0, ACC, tid); __syncthreads(); \
  phaseY<RR, OO, false>(A, Sm, PP0, PP1, ACC, x0, y0, tid); __syncthreads();
#define STEP(RR, OO, PPW, PPR) \
  phaseX<RR, OO, true, true>(gray, A, Sm, PPR, ACC, tid); __syncthreads(); \
  phaseY<RR, OO, true>(A, Sm, PPW, PPR, ACC, x0, y0, tid); __syncthreads();

  STEP0(1, 0)                 // s0  writes PP0
  STEP(1, 3,   PP1, PP0)      // s1
  STEP(1, 6,   PP0, PP1)      // s2
  STEP(2, 9,   PP1, PP0)      // s3
  STEP(2, 14,  PP0, PP1)      // s4
  STEP(2, 19,  PP1, PP0)      // s5
  STEP(3, 24,  PP0, PP1)      // s6
  STEP(3, 31,  PP1, PP0)      // s7
  STEP(3, 38,  PP0, PP1)      // s8
  STEP(4, 45,  PP1, PP0)      // s9
  STEP(4, 54,  PP0, PP1)      // s10
  STEP(4, 63,  PP1, PP0)      // s11
  STEP(5, 72,  PP0, PP1)      // s12
  STEP(5, 83,  PP1, PP0)      // s13
  STEP(5, 94,  PP0, PP1)      // s14
  STEP(6, 105, PP1, PP0)      // s15
  STEP(6, 118, PP0, PP1)      // s16
  STEP(6, 131, PP1, PP0)      // s17
  STEP(7, 144, PP0, PP1)      // s18
  STEP(7, 159, PP1, PP0)      // s19
  STEP(7, 174, PP0, PP1)      // s20 writes PP0
#undef STEP
#undef STEP0

  // ---- drain: P3 rows 0-23 of s20, then rows 24-31 (both read PP0)
  phaseX<1, 0, false, true>(gray, A, Sm, PP0, ACC, tid);
  __syncthreads();
  if (tid < 64) p3_item(192 + tid, Sm, PP0, ACC);
  __syncthreads();   // epilogue reads slots written by other threads

  // ---- output: slot tid == output (row=tid>>3, cols 8*(tid&7)..+7)
  {
    const int row = tid >> 3, cg = tid & 7;
    const float4 lo = *(const float4*)&ACC[tid*ACCSTR];
    const float4 hi = *(const float4*)&ACC[tid*ACCSTR + 4];
    float* op = out + ((size_t)b * IMG + (y0 + row)) * IMG + x0 + 8*cg;
    *(float4*)&op[0] = lo;
    *(float4*)&op[4] = hi;
  }
}

extern "C" void kernel_launch(void* const* d_in, const int* in_sizes, int n_in,
                              void* d_out, int out_size, void* d_ws, size_t ws_size,
                              hipStream_t stream) {
  (void)in_sizes; (void)n_in; (void)d_ws; (void)ws_size; (void)out_size;
  const float* in = (const float*)d_in[0];
  float* out = (float*)d_out;
  dim3 grid(IMG / TW, IMG / TH, 16);
  MultiscaleLoG_kernel<<<grid, dim3(256), 0, stream>>>(in, out);
}

// Round 9
// 653.765 us; speedup vs baseline: 3.2172x; 1.2120x over previous
//
#include <hip/hip_runtime.h>
#include <math.h>

#define TW 64
#define TH 32
#define IMG 1024

#define GSTR 80    // grayb (bf16): 48 rows x 80 cols; b64 lane pattern <=2-way = free
#define ASTR 84    // A (vblur): 34 rows; 84%32=20 -> row-lane reads conflict-free
#define SSTR 68    // S: 34 rows; 68%32=4 -> row-lane reads 2-way = free; rows 16B-aligned
#define ACCSTR 12  // per-thread acc: 8 floats @ stride 12 -> b128 rmw conflict-free
#define WCUT 1e-5f // compile-time tap cutoff (dropped mass ~3e-6/pass, negligible)

// ---- compile-time Gaussian weights: indexed only with constants -> inline literals.
constexpr double cexp_pos(double t) {
  double term = 1.0, sum = 1.0;
  for (int i = 1; i < 120; ++i) { term *= t / i; sum += term; if (term < 1e-300) break; }
  return sum;
}
constexpr double cexp(double t) { return t < 0 ? 1.0 / cexp_pos(-t) : cexp_pos(t); }

struct WTab {
  float w[189];
  constexpr WTab() : w{} {
    int off = 0;
    for (int ki = 0; ki < 7; ++ki) {
      const int ks = 3 + 2 * ki, r = ks >> 1;
      for (int si = 0; si < 3; ++si) {
        const double s = (double)(1 + si);
        double tmp[15] = {}; double sum = 0.0;
        for (int i = 0; i < ks; ++i) {
          const double x = (double)(i - r);
          tmp[i] = cexp(-x * x / (2.0 * s * s)); sum += tmp[i];
        }
        for (int i = 0; i < ks; ++i) w[off + i] = (float)(tmp[i] / sum);
        off += ks;
      }
    }
  }
};
constexpr WTab WT{};

// round-to-nearest-even fp32 -> bf16 (inputs are finite, non-NaN)
__device__ __forceinline__ unsigned short f2bf(float f) {
  const unsigned u = __float_as_uint(f);
  return (unsigned short)((u + 0x7fffu + ((u >> 16) & 1u)) >> 16);
}

// Per-scale processing. R = radius (ksize = 2R+1), OFF = offset into WT.w.
template<int R, int OFF>
__device__ __forceinline__ void do_scale(
    const unsigned short* __restrict__ grayb, float* __restrict__ A,
    float* __restrict__ S, float* __restrict__ ACC, int tid, int x0, int y0)
{
  // ---- P1: vertical blur grayb -> A. 20 quads x 9 row-segments (8x G=4 + 1x G=2).
  // b64 read = 4 bf16 cols; unpack via 16-bit shifts (bf16 -> f32 exact).
  if (tid < 180) {
    const int q   = tid % 20;
    const int seg = tid / 20;
    const int ys  = seg * 4;
    const bool full = (seg < 8);             // seg 8 computes only rows 32,33
    float4 a4[4];
#pragma unroll
    for (int gi = 0; gi < 4; ++gi) a4[gi] = make_float4(0.f, 0.f, 0.f, 0.f);
#pragma unroll
    for (int kk = 0; kk < 4 + 2*R; ++kk) {
      const bool kok = (kk < 2 + 2*R);
      if (full || kok) {
        const uint2 g2 = *(const uint2*)&grayb[(ys + 7 - R + kk)*GSTR + 4*q];
        const float v0 = __uint_as_float(g2.x << 16);
        const float v1 = __uint_as_float(g2.x & 0xffff0000u);
        const float v2 = __uint_as_float(g2.y << 16);
        const float v3 = __uint_as_float(g2.y & 0xffff0000u);
#pragma unroll
        for (int gi = 0; gi < 4; ++gi) {
          const int d = kk - gi;             // tap index 0..2R (compile-time)
          if (d >= 0 && d <= 2*R) {
            if (WT.w[OFF + d] >= WCUT) {     // compile-time tap skip
              if (gi < 2 || full) {
                const float wt = WT.w[OFF + d];   // inline literal
                a4[gi].x += wt * v0;
                a4[gi].y += wt * v1;
                a4[gi].z += wt * v2;
                a4[gi].w += wt * v3;
              }
            }
          }
        }
      }
    }
#pragma unroll
    for (int gi = 0; gi < 4; ++gi)
      if (gi < 2 || full)
        *(float4*)&A[(ys + gi)*ASTR + 4*q] = a4[gi];
  }
  __syncthreads();

  // ---- P2: horizontal blur A -> S (34 rows x 66 cols), force 0 outside image.
  // ar = u%34: consecutive lanes step ROWS (bank step 20) -> conflict-free.
  {
    constexpr int Q0   = (7 - R) >> 2;
    constexpr int NQ   = ((14 + R) >> 2) - Q0 + 1;
    constexpr int BASE = 7 - R - 4*Q0;
#pragma unroll 1
    for (int u = tid; u < 306; u += 256) {             // 34 rows * 9 col-groups
      const int ar = u % 34, cg = u / 34;
      float av[4*NQ];
#pragma unroll
      for (int i = 0; i < NQ; ++i)
        *(float4*)&av[4*i] = *(const float4*)&A[ar*ASTR + 8*cg + 4*(Q0 + i)];
      const int gy  = y0 - 1 + ar;
      const int gx0 = x0 - 1 + 8*cg;
      const bool rowok = ((unsigned)gy < (unsigned)IMG);
      float o8[8];
#pragma unroll
      for (int o = 0; o < 8; ++o) {
        float s = 0.f;
#pragma unroll
        for (int t = 0; t <= 2*R; ++t)
          if (WT.w[OFF + t] >= WCUT)                   // compile-time tap skip
            s += WT.w[OFF + t] * av[o + BASE + t];
        const int gx = gx0 + o;
        // Laplacian input is smooth zero-padded by 1: outside-image slots are 0.
        o8[o] = (rowok && ((unsigned)gx < (unsigned)IMG)) ? s : 0.f;
      }
      if (cg < 8) {
        *(float4*)&S[ar*SSTR + 8*cg]     = make_float4(o8[0], o8[1], o8[2], o8[3]);
        *(float4*)&S[ar*SSTR + 8*cg + 4] = make_float4(o8[4], o8[5], o8[6], o8[7]);
      } else {
        S[ar*SSTR + 64] = o8[0];
        S[ar*SSTR + 65] = o8[1];
      }
    }
  }
  __syncthreads();

  // ---- P3: 5-point Laplacian of S; accumulate |log| into LDS-resident ACC.
  // row = tid&31: consecutive lanes step rows (bank step 4) -> conflict-free.
  {
    const int row = tid & 31, cg = tid >> 5;
    float T[12], M[12], B[12];
#pragma unroll
    for (int i = 0; i < 3; ++i) {
      *(float4*)&T[4*i] = *(const float4*)&S[(row    )*SSTR + 8*cg + 4*i];
      *(float4*)&M[4*i] = *(const float4*)&S[(row + 1)*SSTR + 8*cg + 4*i];
      *(float4*)&B[4*i] = *(const float4*)&S[(row + 2)*SSTR + 8*cg + 4*i];
    }
    float4 aA = *(const float4*)&ACC[tid*ACCSTR];
    float4 aB = *(const float4*)&ACC[tid*ACCSTR + 4];
    float lg;
#define LAP(j) (T[j] + B[j] + M[(j)-1] + M[(j)+1] - 4.f*M[j])
    lg = LAP(1); aA.x += fabsf(lg);
    lg = LAP(2); aA.y += fabsf(lg);
    lg = LAP(3); aA.z += fabsf(lg);
    lg = LAP(4); aA.w += fabsf(lg);
    lg = LAP(5); aB.x += fabsf(lg);
    lg = LAP(6); aB.y += fabsf(lg);
    lg = LAP(7); aB.z += fabsf(lg);
    lg = LAP(8); aB.w += fabsf(lg);
#undef LAP
    *(float4*)&ACC[tid*ACCSTR]     = aA;
    *(float4*)&ACC[tid*ACCSTR + 4] = aB;
  }
  // NO barrier here: next P1 writes A (disjoint from S); the post-P1 barrier
  // orders this P3's S-reads against the next P2's S-writes. ACC is per-thread.
}

__global__ __launch_bounds__(256, 3)
void MultiscaleLoG_kernel(const float* __restrict__ in, float* __restrict__ out)
{
  // Declaration order matters: A's <=348B read-overshoot (cg=8 dead lanes, R=7)
  // must land in S, not past the LDS block.
  __shared__ __align__(16) unsigned short grayb[48*GSTR]; //  7680 B (bf16)
  __shared__ __align__(16) float A[34*ASTR];              // 11424 B
  __shared__ __align__(16) float S[34*SSTR];              //  9248 B
  __shared__ __align__(16) float ACC[256*ACCSTR];         // 12288 B -> 40640 total
                                                          // = 40960 granule -> 4 blocks/CU
  const int tid = threadIdx.x;
  const int x0 = blockIdx.x * TW;
  const int y0 = blockIdx.y * TH;
  const int b  = blockIdx.z;
  const float* __restrict__ base = in + (size_t)b * 3u * 1048576u;

  // zero own ACC slot (per-thread private; pad floats 8..11 never read)
  *(float4*)&ACC[tid*ACCSTR]     = make_float4(0.f, 0.f, 0.f, 0.f);
  *(float4*)&ACC[tid*ACCSTR + 4] = make_float4(0.f, 0.f, 0.f, 0.f);

  // ---- stage gray = channel mean with halo (rows y0-8..y0+39, cols x0-8..x0+71),
  //      rounded to bf16 (RNE); zero outside image.
  const bool interior = (x0 >= 8) & (x0 + 72 <= IMG) & (y0 >= 8) & (y0 + 40 <= IMG);
#pragma unroll 1
  for (int u = tid; u < 960; u += 256) {          // 20 quads x 48 rows
    const int q = u % 20, gr = u / 20;
    const int gx = x0 - 8 + 4*q, gy = y0 - 8 + gr;
    float4 v;
    if (interior) {
      const float* p = base + (size_t)gy * IMG + gx;
      const float4 c0 = *(const float4*)p;
      const float4 c1 = *(const float4*)(p + 1048576);
      const float4 c2 = *(const float4*)(p + 2097152);
      v.x = (c0.x + c1.x + c2.x) * (1.f/3.f);
      v.y = (c0.y + c1.y + c2.y) * (1.f/3.f);
      v.z = (c0.z + c1.z + c2.z) * (1.f/3.f);
      v.w = (c0.w + c1.w + c2.w) * (1.f/3.f);
    } else {
      float t4[4];
#pragma unroll
      for (int j = 0; j < 4; ++j) {
        const int xx = gx + j;
        float s = 0.f;
        if ((unsigned)xx < (unsigned)IMG && (unsigned)gy < (unsigned)IMG) {
          const float* p = base + (size_t)gy * IMG + xx;
          s = (p[0] + p[1048576] + p[2097152]) * (1.f/3.f);
        }
        t4[j] = s;
      }
      v = make_float4(t4[0], t4[1], t4[2], t4[3]);
    }
    uint2 pk;
    pk.x = (unsigned)f2bf(v.x) | ((unsigned)f2bf(v.y) << 16);
    pk.y = (unsigned)f2bf(v.z) | ((unsigned)f2bf(v.w) << 16);
    *(uint2*)&grayb[gr*GSTR + 4*q] = pk;
  }
  __syncthreads();

#define DO_KS(R, KOFF) \
  do_scale<R, (KOFF)>(grayb, A, S, ACC, tid, x0, y0); \
  do_scale<R, (KOFF) + (2*(R)+1)>(grayb, A, S, ACC, tid, x0, y0); \
  do_scale<R, (KOFF) + 2*(2*(R)+1)>(grayb, A, S, ACC, tid, x0, y0);

  DO_KS(1, 0)
  DO_KS(2, 9)
  DO_KS(3, 24)
  DO_KS(4, 45)
  DO_KS(5, 72)
  DO_KS(6, 105)
  DO_KS(7, 144)
#undef DO_KS

  // ---- coalesced output straight from ACC (one-time permuted LDS read).
  // BARRIER REQUIRED: the read crosses threads/waves (owner != tid).
  __syncthreads();
  {
    const int cg = tid & 7, row = tid >> 3;     // output ownership
    const int owner = (cg << 5) | row;          // thread that accumulated it
    const float4 lo = *(const float4*)&ACC[owner*ACCSTR];
    const float4 hi = *(const float4*)&ACC[owner*ACCSTR + 4];
    float* op = out + ((size_t)b * IMG + (y0 + row)) * IMG + x0 + 8*cg;
    *(float4*)&op[0] = lo;
    *(float4*)&op[4] = hi;
  }
}

extern "C" void kernel_launch(void* const* d_in, const int* in_sizes, int n_in,
                              void* d_out, int out_size, void* d_ws, size_t ws_size,
                              hipStream_t stream) {
  (void)in_sizes; (void)n_in; (void)d_ws; (void)ws_size; (void)out_size;
  const float* in = (const float*)d_in[0];
  float* out = (float*)d_out;
  dim3 grid(IMG / TW, IMG / TH, 16);
  MultiscaleLoG_kernel<<<grid, dim3(256), 0, stream>>>(in, out);
}

// Round 10
// 598.943 us; speedup vs baseline: 3.5116x; 1.0915x over previous
//
#include <hip/hip_runtime.h>
#include <math.h>

#define TW 64
#define TH 32
#define IMG 1024

#define GSTR 80    // grayb (bf16): 48 rows x 80 cols; b64 lane pattern <=2-way = free
#define ASTR 84    // Abf (bf16): 34 rows x 84 ushort; byte stride 168 -> bank step 10
                   //   -> P2 row-stepping b64 reads <=2-way = free
#define SSTR 68    // S (fp32): 34 rows; 68%32=4 -> row-lane reads 2-way = free
#define WCUT 1e-5f // compile-time tap cutoff (dropped mass ~3e-6/pass, negligible)

// ---- compile-time Gaussian weights: indexed only with constants -> inline literals.
constexpr double cexp_pos(double t) {
  double term = 1.0, sum = 1.0;
  for (int i = 1; i < 120; ++i) { term *= t / i; sum += term; if (term < 1e-300) break; }
  return sum;
}
constexpr double cexp(double t) { return t < 0 ? 1.0 / cexp_pos(-t) : cexp_pos(t); }

struct WTab {
  float w[189];
  constexpr WTab() : w{} {
    int off = 0;
    for (int ki = 0; ki < 7; ++ki) {
      const int ks = 3 + 2 * ki, r = ks >> 1;
      for (int si = 0; si < 3; ++si) {
        const double s = (double)(1 + si);
        double tmp[15] = {}; double sum = 0.0;
        for (int i = 0; i < ks; ++i) {
          const double x = (double)(i - r);
          tmp[i] = cexp(-x * x / (2.0 * s * s)); sum += tmp[i];
        }
        for (int i = 0; i < ks; ++i) w[off + i] = (float)(tmp[i] / sum);
        off += ks;
      }
    }
  }
};
constexpr WTab WT{};

// round-to-nearest-even fp32 -> bf16 (inputs are finite, non-NaN)
__device__ __forceinline__ unsigned f2bf(float f) {
  const unsigned u = __float_as_uint(f);
  return (u + 0x7fffu + ((u >> 16) & 1u)) >> 16;
}
__device__ __forceinline__ unsigned pk2bf(float lo, float hi) {
  return f2bf(lo) | (f2bf(hi) << 16);
}

// Per-scale processing. R = radius (ksize = 2R+1), OFF = offset into WT.w.
template<int R, int OFF>
__device__ __forceinline__ void do_scale(
    const unsigned short* __restrict__ grayb, unsigned short* __restrict__ Abf,
    float* __restrict__ S, float4* __restrict__ ACCA, float4* __restrict__ ACCB,
    int tid, int x0, int y0)
{
  // ---- P1: vertical blur grayb -> Abf. 20 quads x 9 row-segments (8x G=4 + 1x G=2).
  if (tid < 180) {
    const int q   = tid % 20;
    const int seg = tid / 20;
    const int ys  = seg * 4;
    const bool full = (seg < 8);             // seg 8 computes only rows 32,33
    float4 a4[4];
#pragma unroll
    for (int gi = 0; gi < 4; ++gi) a4[gi] = make_float4(0.f, 0.f, 0.f, 0.f);
#pragma unroll
    for (int kk = 0; kk < 4 + 2*R; ++kk) {
      const bool kok = (kk < 2 + 2*R);
      if (full || kok) {
        const uint2 g2 = *(const uint2*)&grayb[(ys + 7 - R + kk)*GSTR + 4*q];
        const float v0 = __uint_as_float(g2.x << 16);
        const float v1 = __uint_as_float(g2.x & 0xffff0000u);
        const float v2 = __uint_as_float(g2.y << 16);
        const float v3 = __uint_as_float(g2.y & 0xffff0000u);
#pragma unroll
        for (int gi = 0; gi < 4; ++gi) {
          const int d = kk - gi;             // tap index 0..2R (compile-time)
          if (d >= 0 && d <= 2*R) {
            if (WT.w[OFF + d] >= WCUT) {     // compile-time tap skip
              if (gi < 2 || full) {
                const float wt = WT.w[OFF + d];   // inline literal
                a4[gi].x += wt * v0;
                a4[gi].y += wt * v1;
                a4[gi].z += wt * v2;
                a4[gi].w += wt * v3;
              }
            }
          }
        }
      }
    }
#pragma unroll
    for (int gi = 0; gi < 4; ++gi)
      if (gi < 2 || full) {
        uint2 pk;
        pk.x = pk2bf(a4[gi].x, a4[gi].y);
        pk.y = pk2bf(a4[gi].z, a4[gi].w);
        *(uint2*)&Abf[(ys + gi)*ASTR + 4*q] = pk;
      }
  }
  __syncthreads();

  // ---- P2: horizontal blur Abf -> S (34 rows x 66 cols), force 0 outside image.
  // ar = u%34: consecutive lanes step ROWS (byte stride 168, bank step 10) -> free.
  {
    constexpr int Q0   = (7 - R) >> 2;
    constexpr int NQ   = ((14 + R) >> 2) - Q0 + 1;
    constexpr int BASE = 7 - R - 4*Q0;
#pragma unroll 1
    for (int u = tid; u < 306; u += 256) {             // 34 rows * 9 col-groups
      const int ar = u % 34, cg = u / 34;
      float av[4*NQ];
#pragma unroll
      for (int i = 0; i < NQ; ++i) {
        const uint2 g2 = *(const uint2*)&Abf[ar*ASTR + 8*cg + 4*(Q0 + i)];
        av[4*i]     = __uint_as_float(g2.x << 16);
        av[4*i + 1] = __uint_as_float(g2.x & 0xffff0000u);
        av[4*i + 2] = __uint_as_float(g2.y << 16);
        av[4*i + 3] = __uint_as_float(g2.y & 0xffff0000u);
      }
      const int gy  = y0 - 1 + ar;
      const int gx0 = x0 - 1 + 8*cg;
      const bool rowok = ((unsigned)gy < (unsigned)IMG);
      float o8[8];
#pragma unroll
      for (int o = 0; o < 8; ++o) {
        float s = 0.f;
#pragma unroll
        for (int t = 0; t <= 2*R; ++t)
          if (WT.w[OFF + t] >= WCUT)                   // compile-time tap skip
            s += WT.w[OFF + t] * av[o + BASE + t];
        const int gx = gx0 + o;
        // Laplacian input is smooth zero-padded by 1: outside-image slots are 0.
        o8[o] = (rowok && ((unsigned)gx < (unsigned)IMG)) ? s : 0.f;
      }
      if (cg < 8) {
        *(float4*)&S[ar*SSTR + 8*cg]     = make_float4(o8[0], o8[1], o8[2], o8[3]);
        *(float4*)&S[ar*SSTR + 8*cg + 4] = make_float4(o8[4], o8[5], o8[6], o8[7]);
      } else {
        S[ar*SSTR + 64] = o8[0];
        S[ar*SSTR + 65] = o8[1];
      }
    }
  }
  __syncthreads();

  // ---- P3: 5-point Laplacian of S; accumulate |log| into LDS-resident ACC.
  // row = tid&31: consecutive lanes step rows (bank step 4) -> conflict-free.
  // ACCA/ACCB: per-thread float4 slots, quad step 1 -> 2-way = free.
  {
    const int row = tid & 31, cg = tid >> 5;
    float T[12], M[12], B[12];
#pragma unroll
    for (int i = 0; i < 3; ++i) {
      *(float4*)&T[4*i] = *(const float4*)&S[(row    )*SSTR + 8*cg + 4*i];
      *(float4*)&M[4*i] = *(const float4*)&S[(row + 1)*SSTR + 8*cg + 4*i];
      *(float4*)&B[4*i] = *(const float4*)&S[(row + 2)*SSTR + 8*cg + 4*i];
    }
    float4 aA = ACCA[tid];
    float4 aB = ACCB[tid];
    float lg;
#define LAP(j) (T[j] + B[j] + M[(j)-1] + M[(j)+1] - 4.f*M[j])
    lg = LAP(1); aA.x += fabsf(lg);
    lg = LAP(2); aA.y += fabsf(lg);
    lg = LAP(3); aA.z += fabsf(lg);
    lg = LAP(4); aA.w += fabsf(lg);
    lg = LAP(5); aB.x += fabsf(lg);
    lg = LAP(6); aB.y += fabsf(lg);
    lg = LAP(7); aB.z += fabsf(lg);
    lg = LAP(8); aB.w += fabsf(lg);
#undef LAP
    ACCA[tid] = aA;
    ACCB[tid] = aB;
  }
  // NO barrier here: next P1 writes Abf (disjoint from S); the post-P1 barrier
  // orders this P3's S-reads against the next P2's S-writes. ACC is per-thread.
}

__global__ __launch_bounds__(256, 3)
void MultiscaleLoG_kernel(const float* __restrict__ in, float* __restrict__ out)
{
  // Declaration order matters: Abf's <=16B read-overshoot (cg=8 dead lanes, R=7,
  // last row) must land in S, not past the LDS block.
  __shared__ __align__(16) unsigned short grayb[48*GSTR]; //  7680 B (bf16)
  __shared__ __align__(16) unsigned short Abf[34*ASTR];   //  5712 B (bf16)
  __shared__ __align__(16) float S[34*SSTR];              //  9248 B
  __shared__ __align__(16) float4 ACCA[256];              //  4096 B
  __shared__ __align__(16) float4 ACCB[256];              //  4096 B
  // total 30832 B -> 5 blocks/CU (20 waves, vs 4 blocks at R9's 40640)

  const int tid = threadIdx.x;
  const int x0 = blockIdx.x * TW;
  const int y0 = blockIdx.y * TH;
  const int b  = blockIdx.z;
  const float* __restrict__ base = in + (size_t)b * 3u * 1048576u;

  // zero own ACC slots (per-thread private)
  ACCA[tid] = make_float4(0.f, 0.f, 0.f, 0.f);
  ACCB[tid] = make_float4(0.f, 0.f, 0.f, 0.f);

  // ---- stage gray = channel mean with halo (rows y0-8..y0+39, cols x0-8..x0+71),
  //      rounded to bf16 (RNE); zero outside image.
  const bool interior = (x0 >= 8) & (x0 + 72 <= IMG) & (y0 >= 8) & (y0 + 40 <= IMG);
#pragma unroll 1
  for (int u = tid; u < 960; u += 256) {          // 20 quads x 48 rows
    const int q = u % 20, gr = u / 20;
    const int gx = x0 - 8 + 4*q, gy = y0 - 8 + gr;
    float4 v;
    if (interior) {
      const float* p = base + (size_t)gy * IMG + gx;
      const float4 c0 = *(const float4*)p;
      const float4 c1 = *(const float4*)(p + 1048576);
      const float4 c2 = *(const float4*)(p + 2097152);
      v.x = (c0.x + c1.x + c2.x) * (1.f/3.f);
      v.y = (c0.y + c1.y + c2.y) * (1.f/3.f);
      v.z = (c0.z + c1.z + c2.z) * (1.f/3.f);
      v.w = (c0.w + c1.w + c2.w) * (1.f/3.f);
    } else {
      float t4[4];
#pragma unroll
      for (int j = 0; j < 4; ++j) {
        const int xx = gx + j;
        float s = 0.f;
        if ((unsigned)xx < (unsigned)IMG && (unsigned)gy < (unsigned)IMG) {
          const float* p = base + (size_t)gy * IMG + xx;
          s = (p[0] + p[1048576] + p[2097152]) * (1.f/3.f);
        }
        t4[j] = s;
      }
      v = make_float4(t4[0], t4[1], t4[2], t4[3]);
    }
    uint2 pk;
    pk.x = pk2bf(v.x, v.y);
    pk.y = pk2bf(v.z, v.w);
    *(uint2*)&grayb[gr*GSTR + 4*q] = pk;
  }
  __syncthreads();

#define DO_KS(R, KOFF) \
  do_scale<R, (KOFF)>(grayb, Abf, S, ACCA, ACCB, tid, x0, y0); \
  do_scale<R, (KOFF) + (2*(R)+1)>(grayb, Abf, S, ACCA, ACCB, tid, x0, y0); \
  do_scale<R, (KOFF) + 2*(2*(R)+1)>(grayb, Abf, S, ACCA, ACCB, tid, x0, y0);

  DO_KS(1, 0)
  DO_KS(2, 9)
  DO_KS(3, 24)
  DO_KS(4, 45)
  DO_KS(5, 72)
  DO_KS(6, 105)
  DO_KS(7, 144)
#undef DO_KS

  // ---- coalesced output straight from ACC (one-time permuted LDS read).
  // BARRIER REQUIRED: the read crosses threads/waves (owner != tid).
  __syncthreads();
  {
    const int cg = tid & 7, row = tid >> 3;     // output ownership
    const int owner = (cg << 5) | row;          // thread that accumulated it
    const float4 lo = ACCA[owner];
    const float4 hi = ACCB[owner];
    float* op = out + ((size_t)b * IMG + (y0 + row)) * IMG + x0 + 8*cg;
    *(float4*)&op[0] = lo;
    *(float4*)&op[4] = hi;
  }
}

extern "C" void kernel_launch(void* const* d_in, const int* in_sizes, int n_in,
                              void* d_out, int out_size, void* d_ws, size_t ws_size,
                              hipStream_t stream) {
  (void)in_sizes; (void)n_in; (void)d_ws; (void)ws_size; (void)out_size;
  const float* in = (const float*)d_in[0];
  float* out = (float*)d_out;
  dim3 grid(IMG / TW, IMG / TH, 16);
  MultiscaleLoG_kernel<<<grid, dim3(256), 0, stream>>>(in, out);
}

// Round 11
// 483.407 us; speedup vs baseline: 4.3509x; 1.2390x over previous
//
#include <hip/hip_runtime.h>
#include <math.h>

#define TW 64
#define TH 32
#define IMG 1024

#define GSTR 80    // grayb (bf16): 48 rows x 80 cols; b64 lane pattern <=2-way = free
#define ASTR 84    // Abf (bf16): 34 rows x 84 ushort; byte stride 168 -> bank step 10
#define SSTR 68    // S (fp32): 34 rows; 68%32=4 -> row-lane reads 2-way = free
#define WCUT 1e-5f // compile-time tap cutoff (dropped mass ~3e-6/pass, negligible)

// ---- compile-time Gaussian weights: indexed only with constants -> inline literals.
constexpr double cexp_pos(double t) {
  double term = 1.0, sum = 1.0;
  for (int i = 1; i < 120; ++i) { term *= t / i; sum += term; if (term < 1e-300) break; }
  return sum;
}
constexpr double cexp(double t) { return t < 0 ? 1.0 / cexp_pos(-t) : cexp_pos(t); }

struct WTab {
  float w[189];
  constexpr WTab() : w{} {
    int off = 0;
    for (int ki = 0; ki < 7; ++ki) {
      const int ks = 3 + 2 * ki, r = ks >> 1;
      for (int si = 0; si < 3; ++si) {
        const double s = (double)(1 + si);
        double tmp[15] = {}; double sum = 0.0;
        for (int i = 0; i < ks; ++i) {
          const double x = (double)(i - r);
          tmp[i] = cexp(-x * x / (2.0 * s * s)); sum += tmp[i];
        }
        for (int i = 0; i < ks; ++i) w[off + i] = (float)(tmp[i] / sum);
        off += ks;
      }
    }
  }
};
constexpr WTab WT{};

// round-to-nearest-even fp32 -> bf16 (inputs are finite, non-NaN)
__device__ __forceinline__ unsigned f2bf(float f) {
  const unsigned u = __float_as_uint(f);
  return (u + 0x7fffu + ((u >> 16) & 1u)) >> 16;
}
__device__ __forceinline__ unsigned pk2bf(float lo, float hi) {
  return f2bf(lo) | (f2bf(hi) << 16);
}

// Per-scale processing. R = radius, OFF = offset into WT.w, W = |LoG| multiplicity
// (merged duplicate scales: see call list).
template<int R, int OFF, int W>
__device__ __forceinline__ void do_scale(
    const unsigned short* __restrict__ grayb, unsigned short* __restrict__ Abf,
    float* __restrict__ S, float4* __restrict__ ACCA, float4* __restrict__ ACCB,
    int tid, int x0, int y0)
{
  // ---- P1: vertical blur grayb -> Abf. 20 quads x 9 row-segments (8x G=4 + 1x G=2).
  if (tid < 180) {
    const int q   = tid % 20;
    const int seg = tid / 20;
    const int ys  = seg * 4;
    const bool full = (seg < 8);             // seg 8 computes only rows 32,33
    float4 a4[4];
#pragma unroll
    for (int gi = 0; gi < 4; ++gi) a4[gi] = make_float4(0.f, 0.f, 0.f, 0.f);
#pragma unroll
    for (int kk = 0; kk < 4 + 2*R; ++kk) {
      const bool kok = (kk < 2 + 2*R);
      if (full || kok) {
        const uint2 g2 = *(const uint2*)&grayb[(ys + 7 - R + kk)*GSTR + 4*q];
        const float v0 = __uint_as_float(g2.x << 16);
        const float v1 = __uint_as_float(g2.x & 0xffff0000u);
        const float v2 = __uint_as_float(g2.y << 16);
        const float v3 = __uint_as_float(g2.y & 0xffff0000u);
#pragma unroll
        for (int gi = 0; gi < 4; ++gi) {
          const int d = kk - gi;             // tap index 0..2R (compile-time)
          if (d >= 0 && d <= 2*R) {
            if (WT.w[OFF + d] >= WCUT) {     // compile-time tap skip
              if (gi < 2 || full) {
                const float wt = WT.w[OFF + d];   // inline literal
                a4[gi].x += wt * v0;
                a4[gi].y += wt * v1;
                a4[gi].z += wt * v2;
                a4[gi].w += wt * v3;
              }
            }
          }
        }
      }
    }
#pragma unroll
    for (int gi = 0; gi < 4; ++gi)
      if (gi < 2 || full) {
        uint2 pk;
        pk.x = pk2bf(a4[gi].x, a4[gi].y);
        pk.y = pk2bf(a4[gi].z, a4[gi].w);
        *(uint2*)&Abf[(ys + gi)*ASTR + 4*q] = pk;
      }
  }
  __syncthreads();

  // ---- P2: horizontal blur Abf -> S (34 rows x 66 cols), force 0 outside image.
  // ar = u%34: consecutive lanes step ROWS (byte stride 168, bank step 10) -> free.
  {
    constexpr int Q0   = (7 - R) >> 2;
    constexpr int NQ   = ((14 + R) >> 2) - Q0 + 1;
    constexpr int BASE = 7 - R - 4*Q0;
#pragma unroll 1
    for (int u = tid; u < 306; u += 256) {             // 34 rows * 9 col-groups
      const int ar = u % 34, cg = u / 34;
      float av[4*NQ];
#pragma unroll
      for (int i = 0; i < NQ; ++i) {
        const uint2 g2 = *(const uint2*)&Abf[ar*ASTR + 8*cg + 4*(Q0 + i)];
        av[4*i]     = __uint_as_float(g2.x << 16);
        av[4*i + 1] = __uint_as_float(g2.x & 0xffff0000u);
        av[4*i + 2] = __uint_as_float(g2.y << 16);
        av[4*i + 3] = __uint_as_float(g2.y & 0xffff0000u);
      }
      const int gy  = y0 - 1 + ar;
      const int gx0 = x0 - 1 + 8*cg;
      const bool rowok = ((unsigned)gy < (unsigned)IMG);
      float o8[8];
#pragma unroll
      for (int o = 0; o < 8; ++o) {
        float s = 0.f;
#pragma unroll
        for (int t = 0; t <= 2*R; ++t)
          if (WT.w[OFF + t] >= WCUT)                   // compile-time tap skip
            s += WT.w[OFF + t] * av[o + BASE + t];
        const int gx = gx0 + o;
        // Laplacian input is smooth zero-padded by 1: outside-image slots are 0.
        o8[o] = (rowok && ((unsigned)gx < (unsigned)IMG)) ? s : 0.f;
      }
      if (cg < 8) {
        *(float4*)&S[ar*SSTR + 8*cg]     = make_float4(o8[0], o8[1], o8[2], o8[3]);
        *(float4*)&S[ar*SSTR + 8*cg + 4] = make_float4(o8[4], o8[5], o8[6], o8[7]);
      } else {
        S[ar*SSTR + 64] = o8[0];
        S[ar*SSTR + 65] = o8[1];
      }
    }
  }
  __syncthreads();

  // ---- P3: 5-point Laplacian of S; ACC += W * |log|.
  // row = tid&31: consecutive lanes step rows (bank step 4) -> conflict-free.
  {
    const int row = tid & 31, cg = tid >> 5;
    float T[12], M[12], B[12];
#pragma unroll
    for (int i = 0; i < 3; ++i) {
      *(float4*)&T[4*i] = *(const float4*)&S[(row    )*SSTR + 8*cg + 4*i];
      *(float4*)&M[4*i] = *(const float4*)&S[(row + 1)*SSTR + 8*cg + 4*i];
      *(float4*)&B[4*i] = *(const float4*)&S[(row + 2)*SSTR + 8*cg + 4*i];
    }
    float4 aA = ACCA[tid];
    float4 aB = ACCB[tid];
    const float wm = (float)W;   // 1.0/2.0/4.0 are free inline constants
    float lg;
#define LAP(j) (T[j] + B[j] + M[(j)-1] + M[(j)+1] - 4.f*M[j])
    lg = LAP(1); aA.x += wm * fabsf(lg);
    lg = LAP(2); aA.y += wm * fabsf(lg);
    lg = LAP(3); aA.z += wm * fabsf(lg);
    lg = LAP(4); aA.w += wm * fabsf(lg);
    lg = LAP(5); aB.x += wm * fabsf(lg);
    lg = LAP(6); aB.y += wm * fabsf(lg);
    lg = LAP(7); aB.z += wm * fabsf(lg);
    lg = LAP(8); aB.w += wm * fabsf(lg);
#undef LAP
    ACCA[tid] = aA;
    ACCB[tid] = aB;
  }
  // NO barrier here: next P1 writes Abf (disjoint from S); the post-P1 barrier
  // orders this P3's S-reads against the next P2's S-writes. ACC is per-thread.
}

__global__ __launch_bounds__(256, 3)
void MultiscaleLoG_kernel(const float* __restrict__ in, float* __restrict__ out)
{
  // Declaration order matters: Abf's <=16B read-overshoot (cg=8 dead lanes, R=7,
  // last row) must land in S, not past the LDS block.
  __shared__ __align__(16) unsigned short grayb[48*GSTR]; //  7680 B (bf16)
  __shared__ __align__(16) unsigned short Abf[34*ASTR];   //  5712 B (bf16)
  __shared__ __align__(16) float S[34*SSTR];              //  9248 B
  __shared__ __align__(16) float4 ACCA[256];              //  4096 B
  __shared__ __align__(16) float4 ACCB[256];              //  4096 B
  // total 30832 B -> 5 blocks/CU (20 waves)

  const int tid = threadIdx.x;
  const int x0 = blockIdx.x * TW;
  const int y0 = blockIdx.y * TH;
  const int b  = blockIdx.z;
  const float* __restrict__ base = in + (size_t)b * 3u * 1048576u;

  // zero own ACC slots (per-thread private)
  ACCA[tid] = make_float4(0.f, 0.f, 0.f, 0.f);
  ACCB[tid] = make_float4(0.f, 0.f, 0.f, 0.f);

  // ---- stage gray = channel mean with halo (rows y0-8..y0+39, cols x0-8..x0+71),
  //      rounded to bf16 (RNE); zero outside image.
  const bool interior = (x0 >= 8) & (x0 + 72 <= IMG) & (y0 >= 8) & (y0 + 40 <= IMG);
#pragma unroll 1
  for (int u = tid; u < 960; u += 256) {          // 20 quads x 48 rows
    const int q = u % 20, gr = u / 20;
    const int gx = x0 - 8 + 4*q, gy = y0 - 8 + gr;
    float4 v;
    if (interior) {
      const float* p = base + (size_t)gy * IMG + gx;
      const float4 c0 = *(const float4*)p;
      const float4 c1 = *(const float4*)(p + 1048576);
      const float4 c2 = *(const float4*)(p + 2097152);
      v.x = (c0.x + c1.x + c2.x) * (1.f/3.f);
      v.y = (c0.y + c1.y + c2.y) * (1.f/3.f);
      v.z = (c0.z + c1.z + c2.z) * (1.f/3.f);
      v.w = (c0.w + c1.w + c2.w) * (1.f/3.f);
    } else {
      float t4[4];
#pragma unroll
      for (int j = 0; j < 4; ++j) {
        const int xx = gx + j;
        float s = 0.f;
        if ((unsigned)xx < (unsigned)IMG && (unsigned)gy < (unsigned)IMG) {
          const float* p = base + (size_t)gy * IMG + xx;
          s = (p[0] + p[1048576] + p[2097152]) * (1.f/3.f);
        }
        t4[j] = s;
      }
      v = make_float4(t4[0], t4[1], t4[2], t4[3]);
    }
    uint2 pk;
    pk.x = pk2bf(v.x, v.y);
    pk.y = pk2bf(v.z, v.w);
    *(uint2*)&grayb[gr*GSTR + 4*q] = pk;
  }
  __syncthreads();

  // ---- 17 passes covering the 21 reference scales.
  // Merges (truncated-Gaussian duplicates):
  //  * sigma=1, ks=9/11/13/15: taps |d|>4 are < 1e-5 mass -> identical smooth
  //    (<2e-6 rel). One pass at ks=9 weights with W=4.
  //  * sigma=2, ks=13/15: differ by the +-7 taps (4.4e-4 each) + 0.09% renorm.
  //    One pass at ks=15 weights with W=2 (error ~2e-3 typ, <=0.028 worst).
#define DS(R, OFF, W) do_scale<R, OFF, W>(grayb, Abf, S, ACCA, ACCB, tid, x0, y0);
  DS(1, 0,   1)   // ks3  s1
  DS(1, 3,   1)   // ks3  s2
  DS(1, 6,   1)   // ks3  s3
  DS(2, 9,   1)   // ks5  s1
  DS(2, 14,  1)   // ks5  s2
  DS(2, 19,  1)   // ks5  s3
  DS(3, 24,  1)   // ks7  s1
  DS(3, 31,  1)   // ks7  s2
  DS(3, 38,  1)   // ks7  s3
  DS(4, 45,  4)   // ks9  s1  == ks9+ks11+ks13+ks15 at s1
  DS(4, 54,  1)   // ks9  s2
  DS(4, 63,  1)   // ks9  s3
  DS(5, 83,  1)   // ks11 s2
  DS(5, 94,  1)   // ks11 s3
  DS(7, 159, 2)   // ks15 s2  == ks13+ks15 at s2
  DS(6, 131, 1)   // ks13 s3
  DS(7, 174, 1)   // ks15 s3
#undef DS

  // ---- coalesced output straight from ACC (one-time permuted LDS read).
  // BARRIER REQUIRED: the read crosses threads/waves (owner != tid).
  __syncthreads();
  {
    const int cg = tid & 7, row = tid >> 3;     // output ownership
    const int owner = (cg << 5) | row;          // thread that accumulated it
    const float4 lo = ACCA[owner];
    const float4 hi = ACCB[owner];
    float* op = out + ((size_t)b * IMG + (y0 + row)) * IMG + x0 + 8*cg;
    *(float4*)&op[0] = lo;
    *(float4*)&op[4] = hi;
  }
}

extern "C" void kernel_launch(void* const* d_in, const int* in_sizes, int n_in,
                              void* d_out, int out_size, void* d_ws, size_t ws_size,
                              hipStream_t stream) {
  (void)in_sizes; (void)n_in; (void)d_ws; (void)ws_size; (void)out_size;
  const float* in = (const float*)d_in[0];
  float* out = (float*)d_out;
  dim3 grid(IMG / TW, IMG / TH, 16);
  MultiscaleLoG_kernel<<<grid, dim3(256), 0, stream>>>(in, out);
}

// Round 12
// 458.720 us; speedup vs baseline: 4.5851x; 1.0538x over previous
//
#include <hip/hip_runtime.h>
#include <math.h>

#define TW 64
#define TH 32
#define IMG 1024

#define GSTR 80    // grayb (bf16): 48 rows x 80 cols; b64 lane pattern <=2-way = free
#define ASTR 84    // Abf (bf16): 34 rows x 84 ushort; pair-stride 336B -> bank step 20 -> free
#define SSTR 68    // S (fp32): 34 rows; P3 row-lane reads 2-way = free
#define WCUT 1e-5f // compile-time tap cutoff (dropped mass ~3e-6/pass, negligible)

typedef float v4f __attribute__((ext_vector_type(4)));
typedef float v2f __attribute__((ext_vector_type(2)));

// ---- compile-time Gaussian weights: indexed only with constants -> inline literals.
constexpr double cexp_pos(double t) {
  double term = 1.0, sum = 1.0;
  for (int i = 1; i < 120; ++i) { term *= t / i; sum += term; if (term < 1e-300) break; }
  return sum;
}
constexpr double cexp(double t) { return t < 0 ? 1.0 / cexp_pos(-t) : cexp_pos(t); }

struct WTab {
  float w[189];
  constexpr WTab() : w{} {
    int off = 0;
    for (int ki = 0; ki < 7; ++ki) {
      const int ks = 3 + 2 * ki, r = ks >> 1;
      for (int si = 0; si < 3; ++si) {
        const double s = (double)(1 + si);
        double tmp[15] = {}; double sum = 0.0;
        for (int i = 0; i < ks; ++i) {
          const double x = (double)(i - r);
          tmp[i] = cexp(-x * x / (2.0 * s * s)); sum += tmp[i];
        }
        for (int i = 0; i < ks; ++i) w[off + i] = (float)(tmp[i] / sum);
        off += ks;
      }
    }
  }
};
constexpr WTab WT{};

// bf16 pack/unpack helpers (RNE pack; unpack exact)
__device__ __forceinline__ unsigned f2bf(float f) {
  const unsigned u = __float_as_uint(f);
  return (u + 0x7fffu + ((u >> 16) & 1u)) >> 16;
}
__device__ __forceinline__ unsigned pk2bf(float lo, float hi) {
  return f2bf(lo) | (f2bf(hi) << 16);
}
__device__ __forceinline__ float bflo(unsigned u) { return __uint_as_float(u << 16); }
__device__ __forceinline__ float bfhi(unsigned u) { return __uint_as_float(u & 0xffff0000u); }

// Per-scale processing. R = radius, OFF = offset into WT.w, W = |LoG| multiplicity.
template<int R, int OFF, int W>
__device__ __forceinline__ void do_scale(
    const unsigned short* __restrict__ grayb, unsigned short* __restrict__ Abf,
    float* __restrict__ S, float4* __restrict__ ACCA, float4* __restrict__ ACCB,
    int tid, int x0, int y0)
{
  // ---- P1: vertical blur grayb -> Abf. v4f accumulate -> v_pk_fma_f32 pairs.
  if (tid < 180) {
    const int q   = tid % 20;
    const int seg = tid / 20;
    const int ys  = seg * 4;
    const bool full = (seg < 8);             // seg 8 computes only rows 32,33
    v4f a4[4];
#pragma unroll
    for (int gi = 0; gi < 4; ++gi) a4[gi] = (v4f){0.f, 0.f, 0.f, 0.f};
#pragma unroll
    for (int kk = 0; kk < 4 + 2*R; ++kk) {
      const bool kok = (kk < 2 + 2*R);
      if (full || kok) {
        const uint2 g2 = *(const uint2*)&grayb[(ys + 7 - R + kk)*GSTR + 4*q];
        const v4f v = (v4f){bflo(g2.x), bfhi(g2.x), bflo(g2.y), bfhi(g2.y)};
#pragma unroll
        for (int gi = 0; gi < 4; ++gi) {
          const int d = kk - gi;             // tap index 0..2R (compile-time)
          if (d >= 0 && d <= 2*R) {
            if (WT.w[OFF + d] >= WCUT) {     // compile-time tap skip
              if (gi < 2 || full) {
                const float wt = WT.w[OFF + d];
                const v4f w4 = (v4f){wt, wt, wt, wt};
                a4[gi] = __builtin_elementwise_fma(w4, v, a4[gi]);
              }
            }
          }
        }
      }
    }
#pragma unroll
    for (int gi = 0; gi < 4; ++gi)
      if (gi < 2 || full) {
        uint2 pk;
        pk.x = pk2bf(a4[gi].x, a4[gi].y);
        pk.y = pk2bf(a4[gi].z, a4[gi].w);
        *(uint2*)&Abf[(ys + gi)*ASTR + 4*q] = pk;
      }
  }
  __syncthreads();

  // ---- P2: horizontal blur Abf -> S, ROW-PAIR vectorized (v2f lanes = 2 rows).
  // 153 items = 17 row-pairs x 9 col-groups, one per thread (tid<153).
  // Lane bank: pr steps rows by 2 -> Abf byte stride 336 -> bank step 20 -> free.
  if (tid < 153) {
    constexpr int Q0   = (7 - R) >> 2;
    constexpr int NQ   = ((14 + R) >> 2) - Q0 + 1;
    constexpr int BASE = 7 - R - 4*Q0;
    const int pr = tid % 17, cg = tid / 17;
    const int rA = 2*pr, rB = 2*pr + 1;
    v2f av2[4*NQ];
#pragma unroll
    for (int i = 0; i < NQ; ++i) {
      const uint2 ga = *(const uint2*)&Abf[rA*ASTR + 8*cg + 4*(Q0 + i)];
      const uint2 gb = *(const uint2*)&Abf[rB*ASTR + 8*cg + 4*(Q0 + i)];
      av2[4*i]     = (v2f){bflo(ga.x), bflo(gb.x)};
      av2[4*i + 1] = (v2f){bfhi(ga.x), bfhi(gb.x)};
      av2[4*i + 2] = (v2f){bflo(ga.y), bflo(gb.y)};
      av2[4*i + 3] = (v2f){bfhi(ga.y), bfhi(gb.y)};
    }
    v2f s2[8];
#pragma unroll
    for (int o = 0; o < 8; ++o) s2[o] = (v2f){0.f, 0.f};
#pragma unroll
    for (int t = 0; t <= 2*R; ++t) {
      if (WT.w[OFF + t] >= WCUT) {                     // compile-time tap skip
        const float wt = WT.w[OFF + t];
        const v2f w2 = (v2f){wt, wt};
#pragma unroll
        for (int o = 0; o < 8; ++o)
          s2[o] = __builtin_elementwise_fma(w2, av2[o + BASE + t], s2[o]);
      }
    }
    const int gyA = y0 - 1 + rA, gyB = y0 - 1 + rB;
    const int gx0 = x0 - 1 + 8*cg;
    const bool okA = ((unsigned)gyA < (unsigned)IMG);
    const bool okB = ((unsigned)gyB < (unsigned)IMG);
    float oA[8], oB[8];
#pragma unroll
    for (int o = 0; o < 8; ++o) {
      const bool cok = ((unsigned)(gx0 + o) < (unsigned)IMG);
      // Laplacian input is smooth zero-padded by 1: outside-image slots are 0.
      oA[o] = (okA && cok) ? s2[o].x : 0.f;
      oB[o] = (okB && cok) ? s2[o].y : 0.f;
    }
    if (cg < 8) {
      *(float4*)&S[rA*SSTR + 8*cg]     = make_float4(oA[0], oA[1], oA[2], oA[3]);
      *(float4*)&S[rA*SSTR + 8*cg + 4] = make_float4(oA[4], oA[5], oA[6], oA[7]);
      *(float4*)&S[rB*SSTR + 8*cg]     = make_float4(oB[0], oB[1], oB[2], oB[3]);
      *(float4*)&S[rB*SSTR + 8*cg + 4] = make_float4(oB[4], oB[5], oB[6], oB[7]);
    } else {
      S[rA*SSTR + 64] = oA[0];
      S[rA*SSTR + 65] = oA[1];
      S[rB*SSTR + 64] = oB[0];
      S[rB*SSTR + 65] = oB[1];
    }
  }
  __syncthreads();

  // ---- P3: 5-point Laplacian of S; ACC += W * |log|.
  // row = tid&31: consecutive lanes step rows (bank step 4) -> conflict-free.
  {
    const int row = tid & 31, cg = tid >> 5;
    float T[12], M[12], B[12];
#pragma unroll
    for (int i = 0; i < 3; ++i) {
      *(float4*)&T[4*i] = *(const float4*)&S[(row    )*SSTR + 8*cg + 4*i];
      *(float4*)&M[4*i] = *(const float4*)&S[(row + 1)*SSTR + 8*cg + 4*i];
      *(float4*)&B[4*i] = *(const float4*)&S[(row + 2)*SSTR + 8*cg + 4*i];
    }
    float4 aA = ACCA[tid];
    float4 aB = ACCB[tid];
    const float wm = (float)W;   // 1.0/2.0/4.0 are free inline constants
    float lg;
#define LAP(j) (T[j] + B[j] + M[(j)-1] + M[(j)+1] - 4.f*M[j])
    lg = LAP(1); aA.x += wm * fabsf(lg);
    lg = LAP(2); aA.y += wm * fabsf(lg);
    lg = LAP(3); aA.z += wm * fabsf(lg);
    lg = LAP(4); aA.w += wm * fabsf(lg);
    lg = LAP(5); aB.x += wm * fabsf(lg);
    lg = LAP(6); aB.y += wm * fabsf(lg);
    lg = LAP(7); aB.z += wm * fabsf(lg);
    lg = LAP(8); aB.w += wm * fabsf(lg);
#undef LAP
    ACCA[tid] = aA;
    ACCB[tid] = aB;
  }
  // NO barrier here: next P1 writes Abf (disjoint from S); the post-P1 barrier
  // orders this P3's S-reads against the next P2's S-writes. ACC is per-thread.
}

__global__ __launch_bounds__(256, 3)
void MultiscaleLoG_kernel(const float* __restrict__ in, float* __restrict__ out)
{
  // Declaration order matters: Abf's <=16B read-overshoot (cg=8 dead lanes, R=7,
  // last row) must land in S, not past the LDS block.
  __shared__ __align__(16) unsigned short grayb[48*GSTR]; //  7680 B (bf16)
  __shared__ __align__(16) unsigned short Abf[34*ASTR];   //  5712 B (bf16)
  __shared__ __align__(16) float S[34*SSTR];              //  9248 B
  __shared__ __align__(16) float4 ACCA[256];              //  4096 B
  __shared__ __align__(16) float4 ACCB[256];              //  4096 B
  // total 30832 B -> 5 blocks/CU (20 waves)

  const int tid = threadIdx.x;
  const int x0 = blockIdx.x * TW;
  const int y0 = blockIdx.y * TH;
  const int b  = blockIdx.z;
  const float* __restrict__ base = in + (size_t)b * 3u * 1048576u;

  // zero own ACC slots (per-thread private)
  ACCA[tid] = make_float4(0.f, 0.f, 0.f, 0.f);
  ACCB[tid] = make_float4(0.f, 0.f, 0.f, 0.f);

  // ---- stage gray = channel mean with halo (rows y0-8..y0+39, cols x0-8..x0+71),
  //      rounded to bf16 (RNE); zero outside image.
  const bool interior = (x0 >= 8) & (x0 + 72 <= IMG) & (y0 >= 8) & (y0 + 40 <= IMG);
#pragma unroll 1
  for (int u = tid; u < 960; u += 256) {          // 20 quads x 48 rows
    const int q = u % 20, gr = u / 20;
    const int gx = x0 - 8 + 4*q, gy = y0 - 8 + gr;
    v4f v;
    if (interior) {
      const float* p = base + (size_t)gy * IMG + gx;
      const v4f c0 = *(const v4f*)p;
      const v4f c1 = *(const v4f*)(p + 1048576);
      const v4f c2 = *(const v4f*)(p + 2097152);
      v = (c0 + c1 + c2) * (1.f/3.f);
    } else {
      float t4[4];
#pragma unroll
      for (int j = 0; j < 4; ++j) {
        const int xx = gx + j;
        float s = 0.f;
        if ((unsigned)xx < (unsigned)IMG && (unsigned)gy < (unsigned)IMG) {
          const float* p = base + (size_t)gy * IMG + xx;
          s = (p[0] + p[1048576] + p[2097152]) * (1.f/3.f);
        }
        t4[j] = s;
      }
      v = (v4f){t4[0], t4[1], t4[2], t4[3]};
    }
    uint2 pk;
    pk.x = pk2bf(v.x, v.y);
    pk.y = pk2bf(v.z, v.w);
    *(uint2*)&grayb[gr*GSTR + 4*q] = pk;
  }
  __syncthreads();

  // ---- 17 passes covering the 21 reference scales (merged duplicates:
  //  sigma=1 ks9/11/13/15 -> W=4 at ks9; sigma=2 ks13/15 -> W=2 at ks15).
#define DS(R, OFF, W) do_scale<R, OFF, W>(grayb, Abf, S, ACCA, ACCB, tid, x0, y0);
  DS(1, 0,   1)   // ks3  s1
  DS(1, 3,   1)   // ks3  s2
  DS(1, 6,   1)   // ks3  s3
  DS(2, 9,   1)   // ks5  s1
  DS(2, 14,  1)   // ks5  s2
  DS(2, 19,  1)   // ks5  s3
  DS(3, 24,  1)   // ks7  s1
  DS(3, 31,  1)   // ks7  s2
  DS(3, 38,  1)   // ks7  s3
  DS(4, 45,  4)   // ks9  s1  == ks9+ks11+ks13+ks15 at s1
  DS(4, 54,  1)   // ks9  s2
  DS(4, 63,  1)   // ks9  s3
  DS(5, 83,  1)   // ks11 s2
  DS(5, 94,  1)   // ks11 s3
  DS(7, 159, 2)   // ks15 s2  == ks13+ks15 at s2
  DS(6, 131, 1)   // ks13 s3
  DS(7, 174, 1)   // ks15 s3
#undef DS

  // ---- coalesced output straight from ACC (one-time permuted LDS read).
  // BARRIER REQUIRED: the read crosses threads/waves (owner != tid).
  __syncthreads();
  {
    const int cg = tid & 7, row = tid >> 3;     // output ownership
    const int owner = (cg << 5) | row;          // thread that accumulated it
    const float4 lo = ACCA[owner];
    const float4 hi = ACCB[owner];
    float* op = out + ((size_t)b * IMG + (y0 + row)) * IMG + x0 + 8*cg;
    *(float4*)&op[0] = lo;
    *(float4*)&op[4] = hi;
  }
}

extern "C" void kernel_launch(void* const* d_in, const int* in_sizes, int n_in,
                              void* d_out, int out_size, void* d_ws, size_t ws_size,
                              hipStream_t stream) {
  (void)in_sizes; (void)n_in; (void)d_ws; (void)ws_size; (void)out_size;
  const float* in = (const float*)d_in[0];
  float* out = (float*)d_out;
  dim3 grid(IMG / TW, IMG / TH, 16);
  MultiscaleLoG_kernel<<<grid, dim3(256), 0, stream>>>(in, out);
}